// Round 1
// baseline (79.117 us; speedup 1.0000x reference)
//
#include <hip/hip_runtime.h>
#include <math.h>

// Problem: single_channel_interp  (B=8, D=64, T=512, O=256)
// For each (b,d,o): two-temperature masked softmax over t in [0,T):
//   s    = -alpha*(t_bd[t]-g_bo)^2 + log(max(m,1e-30))
//   s10  = -10*alpha*(...)^2      + log(max(m,1e-30))
//   y      = sum softmax(s)*vals ; w = logsumexp(s) ; y_trans = softmax(s10)*vals
// Since m in {0,1} and alpha>=0, s<=0 and at least one term >= -alpha
// (mask[:,:,0]==1), so no max-shift is needed for fp32 stability.
// Work in log2 domain: exp() -> v_exp_f32, log() -> v_log_f32.

namespace {
constexpr int kB = 8, kD = 64, kT = 512, kO = 256;
constexpr float kLOG2E = 1.4426950408889634f;
constexpr float kLN2   = 0.6931471805599453f;
}

__global__ __launch_bounds__(kO) void interp_kernel(
    const float* __restrict__ x,     // (B, 3D, T)
    const float* __restrict__ grid,  // (B, O)
    const float* __restrict__ kern,  // (D,)
    float* __restrict__ out)         // (B, 3D, O)
{
    __shared__ __align__(16) float s_t[kT];
    __shared__ __align__(16) float s_lm[kT];  // log2(max(mask,1e-30))
    __shared__ __align__(16) float s_v[kT];

    const int bd = blockIdx.x;     // one block per (b,d)
    const int b  = bd >> 6;        // / kD
    const int d  = bd & (kD - 1);
    const int o  = threadIdx.x;    // one thread per output grid point

    const float* base  = x + (size_t)b * (3 * kD * kT);
    const float* vals  = base + (size_t)d * kT;
    const float* mask  = base + (size_t)(kD + d) * kT;
    const float* times = base + (size_t)(2 * kD + d) * kT;

    // Stage the (b,d) row into LDS; precompute log2-mask once per row.
    for (int i = o; i < kT; i += kO) {
        s_v[i]  = vals[i];
        s_t[i]  = times[i];
        s_lm[i] = __builtin_amdgcn_logf(fmaxf(mask[i], 1e-30f)); // v_log_f32 = log2
    }
    __syncthreads();

    // softplus(k) robustly, then scale into log2 domain.
    const float k     = kern[d];
    const float alpha = fmaxf(k, 0.0f) + log1pf(expf(-fabsf(k)));
    const float a2    = alpha * kLOG2E;       // for s
    const float a10   = 10.0f * a2;           // for s10
    const float g     = grid[b * kO + o];

    // 4 independent accumulator chains to break add-latency serialization.
    float l0=0.f,l1=0.f,l2=0.f,l3=0.f;   // sum exp(s)
    float y0=0.f,y1=0.f,y2=0.f,y3=0.f;   // sum exp(s)*v
    float q0=0.f,q1=0.f,q2=0.f,q3=0.f;   // sum exp(s10)
    float z0=0.f,z1=0.f,z2=0.f,z3=0.f;   // sum exp(s10)*v

    #pragma unroll 2
    for (int t = 0; t < kT; t += 4) {
        // All 256 lanes read the same address -> LDS broadcast, conflict-free.
        const float4 tt = *(const float4*)(s_t  + t);
        const float4 lm = *(const float4*)(s_lm + t);
        const float4 vv = *(const float4*)(s_v  + t);

        { float dd = tt.x - g; float nn = dd * dd;
          float p = __builtin_amdgcn_exp2f(fmaf(-a2,  nn, lm.x));
          float r = __builtin_amdgcn_exp2f(fmaf(-a10, nn, lm.x));
          l0 += p; y0 = fmaf(p, vv.x, y0);
          q0 += r; z0 = fmaf(r, vv.x, z0); }
        { float dd = tt.y - g; float nn = dd * dd;
          float p = __builtin_amdgcn_exp2f(fmaf(-a2,  nn, lm.y));
          float r = __builtin_amdgcn_exp2f(fmaf(-a10, nn, lm.y));
          l1 += p; y1 = fmaf(p, vv.y, y1);
          q1 += r; z1 = fmaf(r, vv.y, z1); }
        { float dd = tt.z - g; float nn = dd * dd;
          float p = __builtin_amdgcn_exp2f(fmaf(-a2,  nn, lm.z));
          float r = __builtin_amdgcn_exp2f(fmaf(-a10, nn, lm.z));
          l2 += p; y2 = fmaf(p, vv.z, y2);
          q2 += r; z2 = fmaf(r, vv.z, z2); }
        { float dd = tt.w - g; float nn = dd * dd;
          float p = __builtin_amdgcn_exp2f(fmaf(-a2,  nn, lm.w));
          float r = __builtin_amdgcn_exp2f(fmaf(-a10, nn, lm.w));
          l3 += p; y3 = fmaf(p, vv.w, y3);
          q3 += r; z3 = fmaf(r, vv.w, z3); }
    }

    const float l  = (l0 + l1) + (l2 + l3);
    const float ya = (y0 + y1) + (y2 + y3);
    const float q  = (q0 + q1) + (q2 + q3);
    const float za = (z0 + z1) + (z2 + z3);

    const float w = __builtin_amdgcn_logf(l) * kLN2;  // logsumexp (shift=0)

    float* ob = out + (size_t)b * (3 * kD * kO);
    ob[(size_t)d * kO + o]            = ya / l;   // y
    ob[(size_t)(kD + d) * kO + o]     = w;        // w
    ob[(size_t)(2 * kD + d) * kO + o] = za / q;   // y_trans
}

extern "C" void kernel_launch(void* const* d_in, const int* in_sizes, int n_in,
                              void* d_out, int out_size, void* d_ws, size_t ws_size,
                              hipStream_t stream) {
    const float* x    = (const float*)d_in[0];
    const float* grid = (const float*)d_in[1];
    const float* kern = (const float*)d_in[2];
    float* out        = (float*)d_out;
    interp_kernel<<<dim3(kB * kD), dim3(kO), 0, stream>>>(x, grid, kern, out);
}

// Round 2
// 77.009 us; speedup vs baseline: 1.0274x; 1.0274x over previous
//
#include <hip/hip_runtime.h>
#include <math.h>

// single_channel_interp (B=8, D=64, T=512, O=256)
// R1: latency-bound fix.
//  - 1024-thread blocks: thread = (o = tid&255, quarter = tid>>8), each quarter
//    handles 128 t's -> 512 blocks x 16 waves = 32 waves/CU (was 8).
//  - Linear form: -a*(t-g)^2 + lm = w(t)*g + u(t) + c(o), u/w precomputed
//    per-t into LDS once per block (log2 domain).
//  - Second temperature: exp2(10*arg) = e1^10 via 4 muls (no 2nd v_exp).
//  - Quarter partials combined through LDS (reuses staging buffer).

namespace {
constexpr int kB = 8, kD = 64, kT = 512, kO = 256;
constexpr int kQ = 4;            // T-quarters per block
constexpr int kTH = kO * kQ;     // 1024 threads
constexpr int kTQ = kT / kQ;     // 128 t's per thread
constexpr float kLOG2E = 1.4426950408889634f;
constexpr float kLN2   = 0.6931471805599453f;
}

__global__ __launch_bounds__(kTH, 8) void interp_kernel(
    const float* __restrict__ x,     // (B, 3D, T)
    const float* __restrict__ grid,  // (B, O)
    const float* __restrict__ kern,  // (D,)
    float* __restrict__ out)         // (B, 3D, O)
{
    // Phase 1: smem[0:512]=u, [512:1024]=w, [1024:1536]=v
    // Phase 2: smem[0:4096]= partials [quarter][4 vals][256 o]
    __shared__ __align__(16) float smem[4096];
    float* s_u = smem;
    float* s_w = smem + kT;
    float* s_v = smem + 2 * kT;

    const int tid = threadIdx.x;
    const int o   = tid & (kO - 1);
    const int q   = tid >> 8;         // 0..3
    const int bd  = blockIdx.x;
    const int b   = bd >> 6;
    const int d   = bd & (kD - 1);

    const float* base  = x + (size_t)b * (3 * kD * kT);
    const float* vals  = base + (size_t)d * kT;
    const float* mask  = base + (size_t)(kD + d) * kT;
    const float* times = base + (size_t)(2 * kD + d) * kT;

    // alpha = softplus(kern[d]); work in log2 domain: a2 = alpha*log2(e)
    const float k     = kern[d];
    const float alpha = fmaxf(k, 0.0f) + log1pf(expf(-fabsf(k)));
    const float a2    = alpha * kLOG2E;

    // Stage per-t coefficients (each staged once per block).
    if (tid < kT) {
        const float tt = times[tid];
        const float mm = mask[tid];
        const float lm = __builtin_amdgcn_logf(fmaxf(mm, 1e-30f)); // log2
        s_u[tid] = fmaf(-a2 * tt, tt, lm);   // -a2*t^2 + lm
        s_w[tid] = 2.0f * a2 * tt;           //  2*a2*t
        s_v[tid] = vals[tid];
    }
    __syncthreads();

    const float g = grid[b * kO + o];
    const float c = -a2 * g * g;

    // 4 independent accumulator chains.
    float l0=0.f,l1=0.f,l2=0.f,l3=0.f;
    float y0=0.f,y1=0.f,y2=0.f,y3=0.f;
    float q0=0.f,q1=0.f,q2=0.f,q3=0.f;
    float z0=0.f,z1=0.f,z2=0.f,z3=0.f;

    const int t0 = q * kTQ;
    #pragma unroll 2
    for (int t = t0; t < t0 + kTQ; t += 4) {
        // All lanes read the same LDS address -> broadcast, conflict-free.
        const float4 uu = *(const float4*)(s_u + t);
        const float4 ww = *(const float4*)(s_w + t);
        const float4 vv = *(const float4*)(s_v + t);

        { float e1 = __builtin_amdgcn_exp2f(fmaf(ww.x, g, uu.x) + c);
          float e2 = e1*e1, e4 = e2*e2, e8 = e4*e4, r = e8*e2;
          l0 += e1; y0 = fmaf(e1, vv.x, y0);
          q0 += r;  z0 = fmaf(r,  vv.x, z0); }
        { float e1 = __builtin_amdgcn_exp2f(fmaf(ww.y, g, uu.y) + c);
          float e2 = e1*e1, e4 = e2*e2, e8 = e4*e4, r = e8*e2;
          l1 += e1; y1 = fmaf(e1, vv.y, y1);
          q1 += r;  z1 = fmaf(r,  vv.y, z1); }
        { float e1 = __builtin_amdgcn_exp2f(fmaf(ww.z, g, uu.z) + c);
          float e2 = e1*e1, e4 = e2*e2, e8 = e4*e4, r = e8*e2;
          l2 += e1; y2 = fmaf(e1, vv.z, y2);
          q2 += r;  z2 = fmaf(r,  vv.z, z2); }
        { float e1 = __builtin_amdgcn_exp2f(fmaf(ww.w, g, uu.w) + c);
          float e2 = e1*e1, e4 = e2*e2, e8 = e4*e4, r = e8*e2;
          l3 += e1; y3 = fmaf(e1, vv.w, y3);
          q3 += r;  z3 = fmaf(r,  vv.w, z3); }
    }

    const float lp = (l0 + l1) + (l2 + l3);
    const float yp = (y0 + y1) + (y2 + y3);
    const float qp = (q0 + q1) + (q2 + q3);
    const float zp = (z0 + z1) + (z2 + z3);

    // Combine quarters through LDS (staging data no longer needed).
    __syncthreads();
    smem[(q * 4 + 0) * kO + o] = lp;
    smem[(q * 4 + 1) * kO + o] = yp;
    smem[(q * 4 + 2) * kO + o] = qp;
    smem[(q * 4 + 3) * kO + o] = zp;
    __syncthreads();

    if (q == 0) {
        float l = 0.f, ya = 0.f, qs = 0.f, za = 0.f;
        #pragma unroll
        for (int j = 0; j < kQ; ++j) {
            l  += smem[(j * 4 + 0) * kO + o];
            ya += smem[(j * 4 + 1) * kO + o];
            qs += smem[(j * 4 + 2) * kO + o];
            za += smem[(j * 4 + 3) * kO + o];
        }
        const float w = __builtin_amdgcn_logf(l) * kLN2;  // logsumexp (no shift)
        float* ob = out + (size_t)b * (3 * kD * kO);
        ob[(size_t)d * kO + o]            = ya / l;
        ob[(size_t)(kD + d) * kO + o]     = w;
        ob[(size_t)(2 * kD + d) * kO + o] = za / qs;
    }
}

extern "C" void kernel_launch(void* const* d_in, const int* in_sizes, int n_in,
                              void* d_out, int out_size, void* d_ws, size_t ws_size,
                              hipStream_t stream) {
    const float* x    = (const float*)d_in[0];
    const float* grid = (const float*)d_in[1];
    const float* kern = (const float*)d_in[2];
    float* out        = (float*)d_out;
    interp_kernel<<<dim3(kB * kD), dim3(kTH), 0, stream>>>(x, grid, kern, out);
}